// Round 16
// baseline (89.724 us; speedup 1.0000x reference)
//
#include <hip/hip_runtime.h>

// x:(32,1,512,512) f32, theta:(4,) f32
// out flat (reference raw .view): out_flat[l*128 + b*4 + q] -> float4 units out4[l*32+b]
// Closed form: <Z_q> = cos(th_q)*prod_{S_q} cos(a_r) - sin(th_q)*prod_{T_q} sin(a_r)
// PROBE ROUND: launch the identical (idempotent) kernel TWICE to split
// fixed-harness vs kernel time and measure warm-cache kernel cost.
#define HH 512
#define WW 512
#define HO 256
#define WO 256
#define LTOT (HO * WO)

#define INV_2PI 0.15915494309189535f

typedef float f4 __attribute__((ext_vector_type(4)));

__device__ __forceinline__ f4 qnode(float a0, float a1, float a2, float a3,
                                    const float* __restrict__ ct,
                                    const float* __restrict__ st) {
    float ca[4], sa[4];
    const float r0 = a0 * INV_2PI, r1 = a1 * INV_2PI, r2 = a2 * INV_2PI, r3 = a3 * INV_2PI;
    sa[0] = __builtin_amdgcn_sinf(r0); ca[0] = __builtin_amdgcn_cosf(r0);
    sa[1] = __builtin_amdgcn_sinf(r1); ca[1] = __builtin_amdgcn_cosf(r1);
    sa[2] = __builtin_amdgcn_sinf(r2); ca[2] = __builtin_amdgcn_cosf(r2);
    sa[3] = __builtin_amdgcn_sinf(r3); ca[3] = __builtin_amdgcn_cosf(r3);
    const float A1 = ca[0] * ca[1];
    const float A2 = A1 * ca[2];
    const float A3 = A2 * ca[3];
    const float A0 = (ca[1] * ca[2]) * ca[3];
    const float B0 = sa[0] * sa[1];
    const float B1 = sa[1] * sa[2];
    const float B2 = sa[2] * sa[3];
    const float B3 = B0 * sa[3];
    f4 z;
    z.x = ct[0] * A0 - st[0] * B0;
    z.y = ct[1] * A1 - st[1] * B1;
    z.z = ct[2] * A2 - st[2] * B2;
    z.w = ct[3] * A3 - st[3] * B3;
    return z;
}

__global__ __launch_bounds__(128, 8) void quanv_kernel(const float* __restrict__ x,
                                                       const float* __restrict__ theta,
                                                       float* __restrict__ out) {
    __shared__ f4 lds[512];   // 16 patches x 32 batches (8 KB)

    const int tid   = threadIdx.x;       // 0..127
    const int l0    = blockIdx.x * 16;   // 16 consecutive patches, same image row
    const int irow  = l0 >> 8;
    const int j0    = l0 & 255;
    const int lpair = tid & 7;           // patch-pair -> patches 2*lpair, 2*lpair+1
    const int b0    = tid >> 3;          // 0..15 -> images b0, b0+16

    float ct[4], st[4];
#pragma unroll
    for (int q = 0; q < 4; ++q) {
        const float r = theta[q] * INV_2PI;
        st[q] = __builtin_amdgcn_sinf(r);
        ct[q] = __builtin_amdgcn_cosf(r);
    }

    const int col  = 2 * (j0 + 2 * lpair);   // 16B aligned
    const int off0 = (2 * irow) * WW + col;  // row 2i
    const int off1 = off0 + WW;              // row 2i+1
    const float* xb0 = x + (size_t)b0 * (HH * WW);
    const float* xb1 = x + (size_t)(b0 + 16) * (HH * WW);

    const f4 r0a = *(const f4*)(xb0 + off0);
    const f4 r1a = *(const f4*)(xb0 + off1);
    const f4 r0b = *(const f4*)(xb1 + off0);
    const f4 r1b = *(const f4*)(xb1 + off1);

#pragma unroll
    for (int w = 0; w < 2; ++w) {
        const int b = b0 + 16 * w;
        const f4 r0 = w ? r0b : r0a;
        const f4 r1 = w ? r1b : r1a;
#pragma unroll
        for (int c = 0; c < 2; ++c) {
            const f4 z = qnode(c ? r0.z : r0.x, c ? r0.w : r0.y,
                               c ? r1.z : r1.x, c ? r1.w : r1.y, ct, st);
            const int lsub = 2 * lpair + c;                 // 0..15
            lds[lsub * 32 + (b ^ lsub)] = z;                // XOR swizzle
        }
    }
    __syncthreads();

    f4* o = (f4*)out + (size_t)l0 * 32;
#pragma unroll
    for (int k = 0; k < 4; ++k) {
        const int idx = k * 128 + tid;          // 0..511
        const int ls = idx >> 5, bb = idx & 31;
        __builtin_nontemporal_store(lds[ls * 32 + (bb ^ ls)], &o[idx]);
    }
}

extern "C" void kernel_launch(void* const* d_in, const int* in_sizes, int n_in,
                              void* d_out, int out_size, void* d_ws, size_t ws_size,
                              hipStream_t stream) {
    const float* x     = (const float*)d_in[0];
    const float* theta = (const float*)d_in[1];
    float* out         = (float*)d_out;

    const int blocks = LTOT / 16; // 4096
    // PROBE: two identical launches. Launch 2 runs with warm L3 / drained poison.
    // dur delta vs 81.0 isolates the warm kernel cost (C = 47.7 pinned by R6 rocprof).
    quanv_kernel<<<blocks, 128, 0, stream>>>(x, theta, out);
    quanv_kernel<<<blocks, 128, 0, stream>>>(x, theta, out);
}